// Round 2
// baseline (308.971 us; speedup 1.0000x reference)
//
#include <hip/hip_runtime.h>
#include <hip/hip_bf16.h>
#include <math.h>

typedef __hip_bfloat16 bf16;
typedef __attribute__((ext_vector_type(8))) short bf16x8;
typedef __attribute__((ext_vector_type(4))) float f32x4;

#define GPTR(p) ((const __attribute__((address_space(1))) void*)(p))
#define LPTR(p) ((__attribute__((address_space(3))) void*)(p))

__device__ __forceinline__ float b2f(short s) {
  unsigned int u = ((unsigned int)(unsigned short)s) << 16;
  float f; __builtin_memcpy(&f, &u, 4); return f;
}

// ---------------------------------------------------------------------------
// Merged fp32 -> bf16 conversion for all 5 MFMA operand tensors (1 dispatch).
// ---------------------------------------------------------------------------
__global__ __launch_bounds__(256) void cvt_all(
    const float* __restrict__ x,    const float* __restrict__ w_in,
    const float* __restrict__ w_out,const float* __restrict__ w1,
    const float* __restrict__ w2,
    bf16* __restrict__ xb,   bf16* __restrict__ winb, bf16* __restrict__ woutb,
    bf16* __restrict__ w1b,  bf16* __restrict__ w2b)
{
  const int b = blockIdx.x;
  const float* in; bf16* out; int base;
  if      (b <  4096) { in = x;     out = xb;    base = 0; }
  else if (b <  7168) { in = w_in;  out = winb;  base = 4096; }
  else if (b <  8192) { in = w_out; out = woutb; base = 7168; }
  else if (b < 12288) { in = w1;    out = w1b;   base = 8192; }
  else                { in = w2;    out = w2b;   base = 12288; }
  const int i = ((b - base) * 256 + threadIdx.x) * 4;
  const float4 f = *(const float4*)(in + i);
  ushort4 u;
  u.x = __bfloat16_as_ushort(__float2bfloat16(f.x));
  u.y = __bfloat16_as_ushort(__float2bfloat16(f.y));
  u.z = __bfloat16_as_ushort(__float2bfloat16(f.z));
  u.w = __bfloat16_as_ushort(__float2bfloat16(f.w));
  *(ushort4*)(out + i) = u;
}

__device__ __forceinline__ float gelu_fast(float v) {
  const float u  = 1.5957691216f * (v + 0.044715f * v * v * v);
  const float e  = __expf(u);
  return v * e / (e + 1.0f);
}

// ---------------------------------------------------------------------------
// m201-geometry 256x256 8-phase GEMM (T1+T2+T3+T4+T5), faithful port:
//   BM=BN=256, BK=64, 8 waves (2M x 4N), per-wave 128x64 (8x4 frags).
//   LDS: 2 buffers x 64KB (A[256][64] @0, B[256][64] @32KB), XOR swizzle
//   byte ^= ((row&7)<<4) applied on both pre-swizzled global src + ds_read.
//   Per K-tile, 4 quadrant phases (16 MFMA each):
//     P1: rd A.mi0-3 + B.ni0-1 (12) | stage (T+1).Bhi -> other buf | Q(lo,lo)
//     P2: rd B.ni2-3 (4)           | stage (T+1).Ahi -> other buf | Q(lo,hi)
//     P3: rd A.mi4-7 (8)           | stage (T+2).Blo -> cur buf (B dead) | Q(hi,lo)
//     P4: (regs held)              | stage (T+2).Alo -> cur buf (A dead) | Q(hi,hi)
//   Boundary wait vmcnt(4) only (2 half-tiles of T+2 stay in flight across
//   the barrier); vmcnt(0) at T==NT-2; never drains in steady state.
//   kchunk % 128 == 0 (NT even), M%256==0, N%256==0. Split-K via z; the last
//   z partial can be redirected to Clast (non-uniform workspace slots).
// ---------------------------------------------------------------------------
#define RD(BUF, OFF) (*(const bf16x8*)(((const char*)lds) + (BUF)*65536 + (OFF)))
#define STG(GP, SRC, LOFF)                                                    \
  __builtin_amdgcn_global_load_lds(GPTR((GP) + (SRC)),                        \
                                   LPTR(((char*)lds) + (LOFF)), 16, 0, 0)
#define STGH(BUF, REGBASE, GP, SARR, KT) do {                                 \
    STG(GP, SARR[0] + ((KT) << 6), (BUF)*65536 + (REGBASE) + ldst);           \
    STG(GP, SARR[1] + ((KT) << 6), (BUF)*65536 + (REGBASE) + 8192 + ldst);    \
  } while (0)
#define MFMA8(MB, NB, AF, BF)                                                 \
    _Pragma("unroll") for (int mi = 0; mi < 4; ++mi)                          \
      _Pragma("unroll") for (int ni = 0; ni < 2; ++ni)                        \
        _Pragma("unroll") for (int ks = 0; ks < 2; ++ks)                      \
          acc[(MB)+mi][(NB)+ni] = __builtin_amdgcn_mfma_f32_16x16x32_bf16(    \
              AF[mi][ks], BF[ni][ks], acc[(MB)+mi][(NB)+ni], 0, 0, 0);

#define KTILE(T, BUF) do {                                                    \
    bf16x8 af[4][2], bl[2][2], bh[2][2];                                      \
    _Pragma("unroll") for (int mi = 0; mi < 4; ++mi) {                        \
      af[mi][0] = RD(BUF, aoff[mi][0]); af[mi][1] = RD(BUF, aoff[mi][1]); }   \
    _Pragma("unroll") for (int ni = 0; ni < 2; ++ni) {                        \
      bl[ni][0] = RD(BUF, boff[ni][0]); bl[ni][1] = RD(BUF, boff[ni][1]); }   \
    if ((T) + 1 < NT) STGH((BUF)^1, 49152, B, bHiS, (T)+1);                   \
    asm volatile("s_waitcnt lgkmcnt(8)" ::: "memory");                        \
    __builtin_amdgcn_s_barrier();                                             \
    asm volatile("s_waitcnt lgkmcnt(0)" ::: "memory");                        \
    __builtin_amdgcn_sched_barrier(0);                                        \
    __builtin_amdgcn_s_setprio(1);                                            \
    MFMA8(0, 0, af, bl);                                                      \
    __builtin_amdgcn_s_setprio(0);                                            \
    __builtin_amdgcn_s_barrier();                                             \
    _Pragma("unroll") for (int ni = 0; ni < 2; ++ni) {                        \
      bh[ni][0] = RD(BUF, boff[2+ni][0]); bh[ni][1] = RD(BUF, boff[2+ni][1]); }\
    if ((T) + 1 < NT) STGH((BUF)^1, 16384, A, aHiS, (T)+1);                   \
    __builtin_amdgcn_s_barrier();                                             \
    asm volatile("s_waitcnt lgkmcnt(0)" ::: "memory");                        \
    __builtin_amdgcn_sched_barrier(0);                                        \
    __builtin_amdgcn_s_setprio(1);                                            \
    MFMA8(0, 2, af, bh);                                                      \
    __builtin_amdgcn_s_setprio(0);                                            \
    __builtin_amdgcn_s_barrier();                                             \
    _Pragma("unroll") for (int mi = 0; mi < 4; ++mi) {                        \
      af[mi][0] = RD(BUF, aoff[4+mi][0]); af[mi][1] = RD(BUF, aoff[4+mi][1]); }\
    if ((T) + 2 < NT) STGH(BUF, 32768, B, bLoS, (T)+2);                       \
    __builtin_amdgcn_s_barrier();                                             \
    asm volatile("s_waitcnt lgkmcnt(0)" ::: "memory");                        \
    __builtin_amdgcn_sched_barrier(0);                                        \
    __builtin_amdgcn_s_setprio(1);                                            \
    MFMA8(4, 0, af, bl);                                                      \
    __builtin_amdgcn_s_setprio(0);                                            \
    __builtin_amdgcn_s_barrier();                                             \
    if ((T) + 2 < NT) STGH(BUF, 0, A, aLoS, (T)+2);                           \
    __builtin_amdgcn_s_setprio(1);                                            \
    MFMA8(4, 2, af, bh);                                                      \
    __builtin_amdgcn_s_setprio(0);                                            \
    if ((T) < NT - 2)       asm volatile("s_waitcnt vmcnt(4)" ::: "memory");  \
    else if ((T) == NT - 2) asm volatile("s_waitcnt vmcnt(0)" ::: "memory");  \
    __builtin_amdgcn_s_barrier();                                             \
  } while (0)

template<int GELU>
__global__ __launch_bounds__(512, 2) void gemm256(
    const bf16* __restrict__ A, int lda,
    const bf16* __restrict__ B, int ldb,
    const float* __restrict__ bias,
    bf16* __restrict__ C, int ldc, long czstride, bf16* __restrict__ Clast,
    int kchunk)
{
  __shared__ __align__(16) bf16 lds[2][32768];

  const int t    = threadIdx.x;          // 0..511
  const int lane = t & 63;
  const int w    = t >> 6;               // 0..7
  const int wm   = w >> 2;               // 0..1  (128-row slice)
  const int wn   = w & 3;                // 0..3  (64-col slice)
  const int lr   = lane & 15;
  const int lq   = lane >> 4;

  // T1: bijective XCD swizzle; x fastest => consecutive wid share A panel.
  const int gx   = gridDim.x, gy = gridDim.y, gz = gridDim.z;
  const int nwg  = gx * gy * gz;
  const int orig = blockIdx.x + gx * (blockIdx.y + gy * blockIdx.z);
  const int qq   = nwg >> 3, rr = nwg & 7;
  const int xcd  = orig & 7;
  const int wid  = (xcd < rr ? xcd * (qq + 1) : rr * (qq + 1) + (xcd - rr) * qq)
                 + (orig >> 3);
  const int n0 = (wid % gx) * 256;
  const int m0 = ((wid / gx) % gy) * 256;
  const int kz = wid / (gx * gy);

  A += (size_t)kz * kchunk;
  B += (size_t)kz * kchunk;
  if (Clast && kz == gz - 1) C = Clast; else C += (size_t)kz * czstride;

  const int NT = kchunk >> 6;

  // staging global sources (element offsets); linear LDS dest, pre-swizzled src
  int aLoS[2], aHiS[2], bLoS[2], bHiS[2];
  #pragma unroll
  for (int r = 0; r < 2; ++r) {
    const int q   = r * 8192 + t * 16;
    const int row = q >> 7;                              // 0..127
    const int col = ((q & 127) ^ ((row & 7) << 4)) >> 1; // bf16 units
    aLoS[r] = (m0 + row) * lda + col;
    aHiS[r] = (m0 + 128 + row) * lda + col;
    bLoS[r] = (n0 + row) * ldb + col;
    bHiS[r] = (n0 + 128 + row) * ldb + col;
  }
  const int ldst = t * 16;               // byte offset within a half region

  // ds_read byte offsets (swizzled)
  int aoff[8][2], boff[4][2];
  #pragma unroll
  for (int mi = 0; mi < 8; ++mi) {
    const int row = wm * 128 + mi * 16 + lr;
    #pragma unroll
    for (int ks = 0; ks < 2; ++ks)
      aoff[mi][ks] = row * 128 + ((ks * 64 + lq * 16) ^ ((row & 7) << 4));
  }
  #pragma unroll
  for (int ni = 0; ni < 4; ++ni) {
    const int row = wn * 64 + ni * 16 + lr;
    #pragma unroll
    for (int ks = 0; ks < 2; ++ks)
      boff[ni][ks] = 32768 + row * 128 + ((ks * 64 + lq * 16) ^ ((row & 7) << 4));
  }

  f32x4 acc[8][4];
  #pragma unroll
  for (int mi = 0; mi < 8; ++mi)
    #pragma unroll
    for (int ni = 0; ni < 4; ++ni)
      acc[mi][ni] = (f32x4){0.f, 0.f, 0.f, 0.f};

  // prologue: tile0 all 4 halves + tile1 {Blo, Alo}; wait tile0 resident.
  STGH(0, 32768, B, bLoS, 0);
  STGH(0, 0,     A, aLoS, 0);
  STGH(0, 49152, B, bHiS, 0);
  STGH(0, 16384, A, aHiS, 0);
  if (NT > 1) {
    STGH(1, 32768, B, bLoS, 1);
    STGH(1, 0,     A, aLoS, 1);
    asm volatile("s_waitcnt vmcnt(4)" ::: "memory");
  } else {
    asm volatile("s_waitcnt vmcnt(0)" ::: "memory");
  }
  __builtin_amdgcn_s_barrier();

  for (int T = 0; T < NT; T += 2) {
    KTILE(T, 0);
    KTILE(T + 1, 1);
  }

  // epilogue: C/D layout col=lane&15, row=(lane>>4)*4+i
  #pragma unroll
  for (int ni = 0; ni < 4; ++ni) {
    const int col = n0 + wn * 64 + ni * 16 + lr;
    const float bv = bias ? bias[col] : 0.f;
    #pragma unroll
    for (int mi = 0; mi < 8; ++mi) {
      const int rowb = m0 + wm * 128 + mi * 16 + lq * 4;
      #pragma unroll
      for (int i = 0; i < 4; ++i) {
        float v = acc[mi][ni][i] + bv;
        if (GELU) v = gelu_fast(v);
        C[(size_t)(rowb + i) * ldc + col] = __float2bfloat16(v);
      }
    }
  }
}

#undef KTILE
#undef MFMA8
#undef STGH
#undef STG
#undef RD

// ---------------------------------------------------------------------------
// Old 128x128 2-phase GEMM (proven on this net) — kept for GEMM3's shape.
// ---------------------------------------------------------------------------
template<int GELU, int RESID>
__global__ __launch_bounds__(256, 4) void gemm_bt(
    const bf16* __restrict__ A, int lda,
    const bf16* __restrict__ B, int ldb,
    const float* __restrict__ bias,
    const void* __restrict__ Rv, int ldr,
    bf16* __restrict__ C, int ldc, long czstride,
    int M, int N, int kchunk)
{
  __shared__ __align__(16) bf16 As[128 * 64];
  __shared__ __align__(16) bf16 Bs[128 * 64];

  const int t    = threadIdx.x;
  const int lane = t & 63;
  const int w    = t >> 6;
  const int wm   = w >> 1;
  const int wn   = w & 1;
  const int lr   = lane & 15;
  const int lq   = lane >> 4;
  const int m0   = blockIdx.y * 128;
  const int n0   = blockIdx.x * 128;
  const int kz   = blockIdx.z;

  A += (size_t)kz * kchunk;
  B += (size_t)kz * kchunk;
  C += (size_t)kz * czstride;

  f32x4 acc[4][4];
  #pragma unroll
  for (int mi = 0; mi < 4; ++mi)
    #pragma unroll
    for (int ni = 0; ni < 4; ++ni)
      acc[mi][ni] = (f32x4){0.f, 0.f, 0.f, 0.f};

  const int wbase = (t & ~63) * 8;

  for (int k0 = 0; k0 < kchunk; k0 += 64) {
    #pragma unroll
    for (int it = 0; it < 4; ++it) {
      const int c    = it * 256 + t;
      const int row  = c >> 3;
      const int csw  = ((c & 7) ^ (row & 7)) << 3;
      const bf16* ga = A + (size_t)(m0 + row) * lda + k0 + csw;
      const bf16* gb = B + (size_t)(n0 + row) * ldb + k0 + csw;
      __builtin_amdgcn_global_load_lds(GPTR(ga), LPTR(&As[it * 2048 + wbase]), 16, 0, 0);
      __builtin_amdgcn_global_load_lds(GPTR(gb), LPTR(&Bs[it * 2048 + wbase]), 16, 0, 0);
    }
    __syncthreads();

    #pragma unroll
    for (int ks = 0; ks < 2; ++ks) {
      const int swz = (((ks * 4 + lq) ^ (lr & 7)) << 3);
      bf16x8 af[4], bfr[4];
      #pragma unroll
      for (int mi = 0; mi < 4; ++mi)
        af[mi] = *(const bf16x8*)&As[(wm * 64 + mi * 16 + lr) * 64 + swz];
      #pragma unroll
      for (int ni = 0; ni < 4; ++ni)
        bfr[ni] = *(const bf16x8*)&Bs[(wn * 64 + ni * 16 + lr) * 64 + swz];
      #pragma unroll
      for (int mi = 0; mi < 4; ++mi)
        #pragma unroll
        for (int ni = 0; ni < 4; ++ni)
          acc[mi][ni] = __builtin_amdgcn_mfma_f32_16x16x32_bf16(af[mi], bfr[ni], acc[mi][ni], 0, 0, 0);
    }
    __syncthreads();
  }

  #pragma unroll
  for (int ni = 0; ni < 4; ++ni) {
    const int col = n0 + wn * 64 + ni * 16 + lr;
    const float bv = bias ? bias[col] : 0.f;
    #pragma unroll
    for (int mi = 0; mi < 4; ++mi) {
      const int rowb = m0 + wm * 64 + mi * 16 + lq * 4;
      #pragma unroll
      for (int i = 0; i < 4; ++i) {
        float v = acc[mi][ni][i] + bv;
        if (GELU) v = gelu_fast(v);
        if (RESID == 1) v += ((const float*)Rv)[(size_t)(rowb + i) * ldr + col];
        if (RESID == 2) v += __bfloat162float(((const bf16*)Rv)[(size_t)(rowb + i) * ldr + col]);
        C[(size_t)(rowb + i) * ldc + col] = __float2bfloat16(v);
      }
    }
  }
}

// ---------------------------------------------------------------------------
// Window-5 causal attention, one WAVE per token. lane = h*4 + c. Scores stay
// register-local; in-place into q-cols (wave t is the sole reader of q[t]).
// ---------------------------------------------------------------------------
__global__ __launch_bounds__(256) void attn_win(bf16* __restrict__ qkv)
{
  const int lane = threadIdx.x & 63;
  const int tk   = blockIdx.x * 4 + (threadIdx.x >> 6);   // token 0..4095
  const int s    = tk & 2047;                             // pos in sequence
  const int doff = (lane >> 2) * 64 + (lane & 3) * 16;    // h*64 + c*16

  const size_t row = (size_t)tk * 3072;

  bf16x8 qa = *(const bf16x8*)&qkv[row + doff];
  bf16x8 qb = *(const bf16x8*)&qkv[row + doff + 8];
  float qf[16];
  #pragma unroll
  for (int e = 0; e < 8; ++e) { qf[e] = b2f(qa[e]); qf[8 + e] = b2f(qb[e]); }

  const int W = (s + 1 < 5) ? (s + 1) : 5;
  float p[5];
  #pragma unroll
  for (int j = 0; j < 5; ++j) {
    const int jc = (j < W) ? j : 0;                       // clamped (valid addr)
    const size_t kr = row - (size_t)jc * 3072 + 1024;
    bf16x8 ka = *(const bf16x8*)&qkv[kr + doff];
    bf16x8 kb = *(const bf16x8*)&qkv[kr + doff + 8];
    float d = 0.f;
    #pragma unroll
    for (int e = 0; e < 8; ++e) d += qf[e] * b2f(ka[e]);
    #pragma unroll
    for (int e = 0; e < 8; ++e) d += qf[8 + e] * b2f(kb[e]);
    d += __shfl_xor(d, 1);
    d += __shfl_xor(d, 2);
    p[j] = (j < W) ? d * 0.125f : -1e30f;                 // 1/sqrt(64); mask
  }

  float mx = fmaxf(fmaxf(fmaxf(p[0], p[1]), fmaxf(p[2], p[3])), p[4]);
  float sum = 0.f;
  #pragma unroll
  for (int j = 0; j < 5; ++j) { p[j] = __expf(p[j] - mx); sum += p[j]; }
  const float inv = 1.f / sum;

  float o[16];
  #pragma unroll
  for (int e = 0; e < 16; ++e) o[e] = 0.f;
  #pragma unroll
  for (int j = 0; j < 5; ++j) {
    const int jc = (j < W) ? j : 0;
    const size_t vr = row - (size_t)jc * 3072 + 2048;
    bf16x8 va = *(const bf16x8*)&qkv[vr + doff];
    bf16x8 vb = *(const bf16x8*)&qkv[vr + doff + 8];
    #pragma unroll
    for (int e = 0; e < 8; ++e) { o[e] += p[j] * b2f(va[e]); o[8 + e] += p[j] * b2f(vb[e]); }
  }

  bf16x8 oa, ob;
  #pragma unroll
  for (int e = 0; e < 8; ++e) {
    oa[e] = (short)__bfloat16_as_ushort(__float2bfloat16(o[e] * inv));
    ob[e] = (short)__bfloat16_as_ushort(__float2bfloat16(o[8 + e] * inv));
  }
  *(bf16x8*)&qkv[row + doff]     = oa;
  *(bf16x8*)&qkv[row + doff + 8] = ob;
}

// ---------------------------------------------------------------------------
// Split-K=2 reduce + fp32 residual + bias + LayerNorm; optionally dual-write
// (bf16 primary + fp32 copy) so the final LN can read the residual from the
// fp32 copy and the bf16 buffer's slot can be recycled as a GEMM6 partial.
// ---------------------------------------------------------------------------
template<int DUAL>
__global__ __launch_bounds__(256) void ln_fuse2(
    const bf16* __restrict__ P0, const bf16* __restrict__ P1, int ldp,
    const float* __restrict__ Rv,
    const float* __restrict__ bias,
    const float* __restrict__ g, const float* __restrict__ bt,
    bf16* __restrict__ out_bf, float* __restrict__ out_f32)
{
  const int tk   = blockIdx.x * 4 + (threadIdx.x >> 6);
  const int lane = threadIdx.x & 63;
  const size_t bp = (size_t)tk * ldp;
  const size_t bo = (size_t)tk * 1024;

  float v[16];
  float sum = 0.f;
  #pragma unroll
  for (int i = 0; i < 16; ++i) {
    const int e = i * 64 + lane;
    float tv = __bfloat162float(P0[bp + e]) + __bfloat162float(P1[bp + e])
             + bias[e] + Rv[bo + e];
    v[i] = tv;
    sum += tv;
  }
  #pragma unroll
  for (int d = 1; d < 64; d <<= 1) sum += __shfl_xor(sum, d);
  const float mu = sum * (1.f / 1024.f);

  float sq = 0.f;
  #pragma unroll
  for (int i = 0; i < 16; ++i) { const float dv = v[i] - mu; sq += dv * dv; }
  #pragma unroll
  for (int d = 1; d < 64; d <<= 1) sq += __shfl_xor(sq, d);
  const float rstd = rsqrtf(sq * (1.f / 1024.f) + 1e-5f);

  #pragma unroll
  for (int i = 0; i < 16; ++i) {
    const int e = i * 64 + lane;
    const float o = (v[i] - mu) * rstd * g[e] + bt[e];
    out_bf[bo + e] = __float2bfloat16(o);
    if (DUAL) out_f32[bo + e] = o;
  }
}

// ---------------------------------------------------------------------------
// Split-K=4 reduce (P0..P2 stride pstr from Pb, P3 separate) + fp32 residual
// + bias + LayerNorm -> fp32 out. Rv may alias out (per-token read-then-write).
// ---------------------------------------------------------------------------
__global__ __launch_bounds__(256) void ln_fuse4(
    const bf16* __restrict__ Pb, long pstr, const bf16* __restrict__ P3,
    const float* __restrict__ Rv,
    const float* __restrict__ bias,
    const float* __restrict__ g, const float* __restrict__ bt,
    float* __restrict__ out)
{
  const int tk   = blockIdx.x * 4 + (threadIdx.x >> 6);
  const int lane = threadIdx.x & 63;
  const size_t bo = (size_t)tk * 1024;

  float v[16];
  float sum = 0.f;
  #pragma unroll
  for (int i = 0; i < 16; ++i) {
    const size_t e = bo + i * 64 + lane;
    const int eb = i * 64 + lane;
    float tv = __bfloat162float(Pb[e]) + __bfloat162float(Pb[e + pstr])
             + __bfloat162float(Pb[e + 2 * pstr]) + __bfloat162float(P3[e])
             + bias[eb] + Rv[e];
    v[i] = tv;
    sum += tv;
  }
  #pragma unroll
  for (int d = 1; d < 64; d <<= 1) sum += __shfl_xor(sum, d);
  const float mu = sum * (1.f / 1024.f);

  float sq = 0.f;
  #pragma unroll
  for (int i = 0; i < 16; ++i) { const float dv = v[i] - mu; sq += dv * dv; }
  #pragma unroll
  for (int d = 1; d < 64; d <<= 1) sq += __shfl_xor(sq, d);
  const float rstd = rsqrtf(sq * (1.f / 1024.f) + 1e-5f);

  #pragma unroll
  for (int i = 0; i < 16; ++i) {
    const size_t e = bo + i * 64 + lane;
    const int eb = i * 64 + lane;
    out[e] = (v[i] - mu) * rstd * g[eb] + bt[eb];
  }
}

// ---------------------------------------------------------------------------
// WS layout (72 MiB exactly):
//   0        : qkv [4096,3072] bf16 / phase2: h [4096,4096]
//   33554432 : x_b [4096,1024]  -> GEMM6 partial z=0
//   41943040 : x1_b [4096,1024] -> GEMM6 partial z=1 (x1 residual kept in d_out)
//   50331648 : w1_b [4096,1024] -> GEMM6 partial z=2
//   58720256 : w2_b [1024,4096]
//   67108864 : w_in_b [3072,1024] + w_out_b -> GEMM6 partial z=3 (8MB slot)
//   73400320 : w_out_b [1024,1024]
// ---------------------------------------------------------------------------
extern "C" void kernel_launch(void* const* d_in, const int* in_sizes, int n_in,
                              void* d_out, int out_size, void* d_ws, size_t ws_size,
                              hipStream_t stream)
{
  const float* x     = (const float*)d_in[0];
  const float* w_in  = (const float*)d_in[1];
  const float* b_in  = (const float*)d_in[2];
  const float* w_out = (const float*)d_in[3];
  const float* b_out = (const float*)d_in[4];
  const float* ln1_g = (const float*)d_in[5];
  const float* ln1_b = (const float*)d_in[6];
  const float* ln2_g = (const float*)d_in[7];
  const float* ln2_b = (const float*)d_in[8];
  const float* w1    = (const float*)d_in[9];
  const float* b1    = (const float*)d_in[10];
  const float* w2    = (const float*)d_in[11];
  const float* b2    = (const float*)d_in[12];
  float* out = (float*)d_out;

  char* ws = (char*)d_ws;
  bf16* qkv     = (bf16*)(ws);
  bf16* h       = (bf16*)(ws);
  bf16* x_b     = (bf16*)(ws + 33554432);
  bf16* x1_b    = (bf16*)(ws + 41943040);
  bf16* w1_b    = (bf16*)(ws + 50331648);
  bf16* w2_b    = (bf16*)(ws + 58720256);
  bf16* w_in_b  = (bf16*)(ws + 67108864);
  bf16* w_out_b = (bf16*)(ws + 73400320);
  bf16* Pbase   = x_b;                       // partials z=0..2, stride 8MB
  bf16* Plast   = w_in_b;                    // partial z=3

  const dim3 blk(256);
  const dim3 blk512(512);

  // 0) fp32 -> bf16 operand conversion (single dispatch)
  cvt_all<<<dim3(16384), blk, 0, stream>>>(x, w_in, w_out, w1, w2,
                                           x_b, w_in_b, w_out_b, w1_b, w2_b);

  // 1) qkv = x @ w_in^T + b_in                      [4096,3072], 192 blocks
  gemm256<0><<<dim3(12, 16, 1), blk512, 0, stream>>>(
      x_b, 1024, w_in_b, 1024, b_in, qkv, 3072, 0, nullptr, 1024);
  // 2) windowed causal attention, in-place into q-cols (wave per token)
  attn_win<<<dim3(1024), blk, 0, stream>>>(qkv);
  // 3) split-K=2: k-cols/v-cols = attn @ w_out^T partials (old 128^2 GEMM)
  gemm_bt<0,0><<<dim3(8, 32, 2), blk, 0, stream>>>(
      qkv, 3072, w_out_b, 1024, nullptr, nullptr, 0,
      qkv + 1024, 3072, 1024, 4096, 1024, 512);
  // 4) x1 = LN(x + P0 + P1 + b_out); dual-write bf16 x1_b + fp32 copy in d_out
  ln_fuse2<1><<<dim3(1024), blk, 0, stream>>>(
      qkv + 1024, qkv + 2048, 3072, x, b_out, ln1_g, ln1_b, x1_b, out);
  // 5) h = gelu(x1 @ w1^T + b1)                     [4096,4096], 256 blocks
  gemm256<1><<<dim3(16, 16, 1), blk512, 0, stream>>>(
      x1_b, 1024, w1_b, 1024, b1, h, 4096, 0, nullptr, 1024);
  // 6) split-K=4: partials of h @ w2^T (256 blocks; z=3 -> Plast slot)
  gemm256<0><<<dim3(4, 16, 4), blk512, 0, stream>>>(
      h, 4096, w2_b, 4096, nullptr, Pbase, 1024, 4194304, Plast, 1024);
  // 7) out(fp32) = LN(x1 + P0..P3 + b2), residual x1 from d_out fp32 copy
  ln_fuse4<<<dim3(1024), blk, 0, stream>>>(
      Pbase, 4194304, Plast, out, b2, ln2_g, ln2_b, out);
}

// Round 3
// 274.012 us; speedup vs baseline: 1.1276x; 1.1276x over previous
//
#include <hip/hip_runtime.h>
#include <hip/hip_bf16.h>
#include <math.h>

typedef __hip_bfloat16 bf16;
typedef __attribute__((ext_vector_type(8))) short bf16x8;
typedef __attribute__((ext_vector_type(4))) float f32x4;

#define GPTR(p) ((const __attribute__((address_space(1))) void*)(p))
#define LPTR(p) ((__attribute__((address_space(3))) void*)(p))

__device__ __forceinline__ float b2f(short s) {
  unsigned int u = ((unsigned int)(unsigned short)s) << 16;
  float f; __builtin_memcpy(&f, &u, 4); return f;
}

// ---------------------------------------------------------------------------
// Merged fp32 -> bf16 conversion for all 5 MFMA operand tensors (1 dispatch).
// ---------------------------------------------------------------------------
__global__ __launch_bounds__(256) void cvt_all(
    const float* __restrict__ x,    const float* __restrict__ w_in,
    const float* __restrict__ w_out,const float* __restrict__ w1,
    const float* __restrict__ w2,
    bf16* __restrict__ xb,   bf16* __restrict__ winb, bf16* __restrict__ woutb,
    bf16* __restrict__ w1b,  bf16* __restrict__ w2b)
{
  const int b = blockIdx.x;
  const float* in; bf16* out; int base;
  if      (b <  4096) { in = x;     out = xb;    base = 0; }
  else if (b <  7168) { in = w_in;  out = winb;  base = 4096; }
  else if (b <  8192) { in = w_out; out = woutb; base = 7168; }
  else if (b < 12288) { in = w1;    out = w1b;   base = 8192; }
  else                { in = w2;    out = w2b;   base = 12288; }
  const int i = ((b - base) * 256 + threadIdx.x) * 4;
  const float4 f = *(const float4*)(in + i);
  ushort4 u;
  u.x = __bfloat16_as_ushort(__float2bfloat16(f.x));
  u.y = __bfloat16_as_ushort(__float2bfloat16(f.y));
  u.z = __bfloat16_as_ushort(__float2bfloat16(f.z));
  u.w = __bfloat16_as_ushort(__float2bfloat16(f.w));
  *(ushort4*)(out + i) = u;
}

__device__ __forceinline__ float gelu_fast(float v) {
  const float u  = 1.5957691216f * (v + 0.044715f * v * v * v);
  const float e  = __expf(u);
  return v * e / (e + 1.0f);
}

// ---------------------------------------------------------------------------
// GEMM: C[M,N](bf16) = A[M,K](lda) * B[N,K]^T(ldb) [+ bias(fp32)] with
// optional fast-GELU epilogue and split-K via z. 128x128 tile, BK=64,
// 4 waves (2x2), 4x4 mfma_f32_16x16x32_bf16 per wave. XOR chunk swizzle ->
// 2-way LDS conflicts (free). __launch_bounds__(256,4) -> 4 blocks/CU.
// Round-3 changes vs round-0 baseline (both low-risk, proven structure kept):
//  * T1 bijective XCD swizzle (m204): consecutive work-ids (x fastest =>
//    shared A row-panel) land on the SAME XCD L2. Targets GEMM6's 3.4x
//    HBM over-fetch (135 MB vs 40 ideal).
//  * Epilogue store loop reordered ni-innermost: the 4 partial-line (32B)
//    stores per output row become temporally adjacent -> L2 write-combine.
//    Targets GEMM5's 1.58x write inflation (52.9 MB vs 33.5 ideal).
// ---------------------------------------------------------------------------
template<int GELU, int RESID>   // RESID: 0 none, 1 fp32, 2 bf16
__global__ __launch_bounds__(256, 4) void gemm_bt(
    const bf16* __restrict__ A, int lda,
    const bf16* __restrict__ B, int ldb,
    const float* __restrict__ bias,
    const void* __restrict__ Rv, int ldr,
    bf16* __restrict__ C, int ldc, long czstride,
    int M, int N, int kchunk)
{
  __shared__ __align__(16) bf16 As[128 * 64];
  __shared__ __align__(16) bf16 Bs[128 * 64];

  const int t    = threadIdx.x;
  const int lane = t & 63;
  const int w    = t >> 6;
  const int wm   = w >> 1;
  const int wn   = w & 1;
  const int lr   = lane & 15;
  const int lq   = lane >> 4;

  // T1: bijective XCD swizzle (m204). HW round-robins orig%8 across XCDs;
  // remap so each XCD owns a contiguous wid range; x fastest in wid.
  const int gx   = gridDim.x, gy = gridDim.y;
  const int nwg  = gx * gy * gridDim.z;
  const int orig = blockIdx.x + gx * (blockIdx.y + gy * blockIdx.z);
  const int qq   = nwg >> 3, rr = nwg & 7;
  const int xcd  = orig & 7;
  const int wid  = (xcd < rr ? xcd * (qq + 1) : rr * (qq + 1) + (xcd - rr) * qq)
                 + (orig >> 3);
  const int n0 = (wid % gx) * 128;
  const int m0 = ((wid / gx) % gy) * 128;
  const int kz = wid / (gx * gy);

  A += (size_t)kz * kchunk;
  B += (size_t)kz * kchunk;
  C += (size_t)kz * czstride;

  f32x4 acc[4][4];
  #pragma unroll
  for (int mi = 0; mi < 4; ++mi)
    #pragma unroll
    for (int ni = 0; ni < 4; ++ni)
      acc[mi][ni] = (f32x4){0.f, 0.f, 0.f, 0.f};

  const int wbase = (t & ~63) * 8;

  for (int k0 = 0; k0 < kchunk; k0 += 64) {
    #pragma unroll
    for (int it = 0; it < 4; ++it) {
      const int c    = it * 256 + t;
      const int row  = c >> 3;
      const int csw  = ((c & 7) ^ (row & 7)) << 3;
      const bf16* ga = A + (size_t)(m0 + row) * lda + k0 + csw;
      const bf16* gb = B + (size_t)(n0 + row) * ldb + k0 + csw;
      __builtin_amdgcn_global_load_lds(GPTR(ga), LPTR(&As[it * 2048 + wbase]), 16, 0, 0);
      __builtin_amdgcn_global_load_lds(GPTR(gb), LPTR(&Bs[it * 2048 + wbase]), 16, 0, 0);
    }
    __syncthreads();

    #pragma unroll
    for (int ks = 0; ks < 2; ++ks) {
      const int swz = (((ks * 4 + lq) ^ (lr & 7)) << 3);
      bf16x8 af[4], bfr[4];
      #pragma unroll
      for (int mi = 0; mi < 4; ++mi)
        af[mi] = *(const bf16x8*)&As[(wm * 64 + mi * 16 + lr) * 64 + swz];
      #pragma unroll
      for (int ni = 0; ni < 4; ++ni)
        bfr[ni] = *(const bf16x8*)&Bs[(wn * 64 + ni * 16 + lr) * 64 + swz];
      #pragma unroll
      for (int mi = 0; mi < 4; ++mi)
        #pragma unroll
        for (int ni = 0; ni < 4; ++ni)
          acc[mi][ni] = __builtin_amdgcn_mfma_f32_16x16x32_bf16(af[mi], bfr[ni], acc[mi][ni], 0, 0, 0);
    }
    __syncthreads();
  }

  // Epilogue, ni innermost: per (mi,i) the 4 stores cover one row's 128
  // contiguous cols back-to-back (write-combine friendly).
  float bvv[4];
  #pragma unroll
  for (int ni = 0; ni < 4; ++ni)
    bvv[ni] = bias ? bias[n0 + wn * 64 + ni * 16 + lr] : 0.f;
  #pragma unroll
  for (int mi = 0; mi < 4; ++mi) {
    const int rowb = m0 + wm * 64 + mi * 16 + lq * 4;
    #pragma unroll
    for (int i = 0; i < 4; ++i) {
      const size_t rb = (size_t)(rowb + i);
      #pragma unroll
      for (int ni = 0; ni < 4; ++ni) {
        const int col = n0 + wn * 64 + ni * 16 + lr;
        float v = acc[mi][ni][i] + bvv[ni];
        if (GELU) v = gelu_fast(v);
        if (RESID == 1) v += ((const float*)Rv)[rb * ldr + col];
        if (RESID == 2) v += __bfloat162float(((const bf16*)Rv)[rb * ldr + col]);
        C[rb * ldc + col] = __float2bfloat16(v);
      }
    }
  }
}

// ---------------------------------------------------------------------------
// Window-5 causal attention, one WAVE per token. lane = h*4 + c. Scores stay
// register-local; in-place into q-cols (wave t is the sole reader of q[t]).
// ---------------------------------------------------------------------------
__global__ __launch_bounds__(256) void attn_win(bf16* __restrict__ qkv)
{
  const int lane = threadIdx.x & 63;
  const int tk   = blockIdx.x * 4 + (threadIdx.x >> 6);   // token 0..4095
  const int s    = tk & 2047;                             // pos in sequence
  const int doff = (lane >> 2) * 64 + (lane & 3) * 16;    // h*64 + c*16

  const size_t row = (size_t)tk * 3072;

  bf16x8 qa = *(const bf16x8*)&qkv[row + doff];
  bf16x8 qb = *(const bf16x8*)&qkv[row + doff + 8];
  float qf[16];
  #pragma unroll
  for (int e = 0; e < 8; ++e) { qf[e] = b2f(qa[e]); qf[8 + e] = b2f(qb[e]); }

  const int W = (s + 1 < 5) ? (s + 1) : 5;
  float p[5];
  #pragma unroll
  for (int j = 0; j < 5; ++j) {
    const int jc = (j < W) ? j : 0;                       // clamped (valid addr)
    const size_t kr = row - (size_t)jc * 3072 + 1024;
    bf16x8 ka = *(const bf16x8*)&qkv[kr + doff];
    bf16x8 kb = *(const bf16x8*)&qkv[kr + doff + 8];
    float d = 0.f;
    #pragma unroll
    for (int e = 0; e < 8; ++e) d += qf[e] * b2f(ka[e]);
    #pragma unroll
    for (int e = 0; e < 8; ++e) d += qf[8 + e] * b2f(kb[e]);
    d += __shfl_xor(d, 1);
    d += __shfl_xor(d, 2);
    p[j] = (j < W) ? d * 0.125f : -1e30f;                 // 1/sqrt(64); mask
  }

  float mx = fmaxf(fmaxf(fmaxf(p[0], p[1]), fmaxf(p[2], p[3])), p[4]);
  float sum = 0.f;
  #pragma unroll
  for (int j = 0; j < 5; ++j) { p[j] = __expf(p[j] - mx); sum += p[j]; }
  const float inv = 1.f / sum;

  float o[16];
  #pragma unroll
  for (int e = 0; e < 16; ++e) o[e] = 0.f;
  #pragma unroll
  for (int j = 0; j < 5; ++j) {
    const int jc = (j < W) ? j : 0;
    const size_t vr = row - (size_t)jc * 3072 + 2048;
    bf16x8 va = *(const bf16x8*)&qkv[vr + doff];
    bf16x8 vb = *(const bf16x8*)&qkv[vr + doff + 8];
    #pragma unroll
    for (int e = 0; e < 8; ++e) { o[e] += p[j] * b2f(va[e]); o[8 + e] += p[j] * b2f(vb[e]); }
  }

  bf16x8 oa, ob;
  #pragma unroll
  for (int e = 0; e < 8; ++e) {
    oa[e] = (short)__bfloat16_as_ushort(__float2bfloat16(o[e] * inv));
    ob[e] = (short)__bfloat16_as_ushort(__float2bfloat16(o[8 + e] * inv));
  }
  *(bf16x8*)&qkv[row + doff]     = oa;
  *(bf16x8*)&qkv[row + doff + 8] = ob;
}

// ---------------------------------------------------------------------------
// Fused split-K reduce + residual + bias + LayerNorm over dim=1024.
// ---------------------------------------------------------------------------
template<int OUTF32, int RESBF16>
__global__ __launch_bounds__(256) void ln_fuse(
    const bf16* __restrict__ P0, const bf16* __restrict__ P1, int ldp,
    const void* __restrict__ Rv,
    const float* __restrict__ bias,
    const float* __restrict__ g, const float* __restrict__ bt,
    void* __restrict__ outv)
{
  const int tk   = blockIdx.x * 4 + (threadIdx.x >> 6);
  const int lane = threadIdx.x & 63;
  const size_t bp = (size_t)tk * ldp;
  const size_t bo = (size_t)tk * 1024;

  float v[16];
  float sum = 0.f;
  #pragma unroll
  for (int i = 0; i < 16; ++i) {
    const int e = i * 64 + lane;
    float t = __bfloat162float(P0[bp + e]) + __bfloat162float(P1[bp + e]) + bias[e];
    if (RESBF16) t += __bfloat162float(((const bf16*)Rv)[bo + e]);
    else         t += ((const float*)Rv)[bo + e];
    v[i] = t;
    sum += t;
  }
  #pragma unroll
  for (int d = 1; d < 64; d <<= 1) sum += __shfl_xor(sum, d);
  const float mu = sum * (1.f / 1024.f);

  float sq = 0.f;
  #pragma unroll
  for (int i = 0; i < 16; ++i) { const float dv = v[i] - mu; sq += dv * dv; }
  #pragma unroll
  for (int d = 1; d < 64; d <<= 1) sq += __shfl_xor(sq, d);
  const float rstd = rsqrtf(sq * (1.f / 1024.f) + 1e-5f);

  #pragma unroll
  for (int i = 0; i < 16; ++i) {
    const int e = i * 64 + lane;
    const float o = (v[i] - mu) * rstd * g[e] + bt[e];
    if (OUTF32) ((float*)outv)[bo + e] = o;
    else        ((bf16*)outv)[bo + e] = __float2bfloat16(o);
  }
}

// ---------------------------------------------------------------------------
// WS layout (72 MB):
//   0        : qkv [4096,3072] bf16 / phase2: h [4096,4096]
//   33554432 : x_b [4096,1024] -> GEMM6 partial P0
//   41943040 : x1_b [4096,1024]
//   50331648 : w1_b [4096,1024] -> GEMM6 partial P1
//   58720256 : w2_b [1024,4096]
//   67108864 : w_in_b [3072,1024]
//   73400320 : w_out_b [1024,1024]
// ---------------------------------------------------------------------------
extern "C" void kernel_launch(void* const* d_in, const int* in_sizes, int n_in,
                              void* d_out, int out_size, void* d_ws, size_t ws_size,
                              hipStream_t stream)
{
  const float* x     = (const float*)d_in[0];
  const float* w_in  = (const float*)d_in[1];
  const float* b_in  = (const float*)d_in[2];
  const float* w_out = (const float*)d_in[3];
  const float* b_out = (const float*)d_in[4];
  const float* ln1_g = (const float*)d_in[5];
  const float* ln1_b = (const float*)d_in[6];
  const float* ln2_g = (const float*)d_in[7];
  const float* ln2_b = (const float*)d_in[8];
  const float* w1    = (const float*)d_in[9];
  const float* b1    = (const float*)d_in[10];
  const float* w2    = (const float*)d_in[11];
  const float* b2    = (const float*)d_in[12];
  float* out = (float*)d_out;

  char* ws = (char*)d_ws;
  bf16* qkv     = (bf16*)(ws);
  bf16* h       = (bf16*)(ws);
  bf16* x_b     = (bf16*)(ws + 33554432);
  bf16* x1_b    = (bf16*)(ws + 41943040);
  bf16* w1_b    = (bf16*)(ws + 50331648);
  bf16* w2_b    = (bf16*)(ws + 58720256);
  bf16* w_in_b  = (bf16*)(ws + 67108864);
  bf16* w_out_b = (bf16*)(ws + 73400320);
  bf16* P0      = x_b;
  bf16* P1      = w1_b;

  const dim3 blk(256);

  // 0) fp32 -> bf16 operand conversion (single dispatch)
  cvt_all<<<dim3(16384), blk, 0, stream>>>(x, w_in, w_out, w1, w2,
                                           x_b, w_in_b, w_out_b, w1_b, w2_b);

  // 1) qkv = x @ w_in^T + b_in                      [4096,3072]
  gemm_bt<0,0><<<dim3(24, 32, 1), blk, 0, stream>>>(
      x_b, 1024, w_in_b, 1024, b_in, nullptr, 0, qkv, 3072, 0, 4096, 3072, 1024);
  // 2) windowed causal attention, in-place into q-cols (wave per token)
  attn_win<<<dim3(1024), blk, 0, stream>>>(qkv);
  // 3) split-K=2: k-cols/v-cols = attn @ w_out^T partials
  gemm_bt<0,0><<<dim3(8, 32, 2), blk, 0, stream>>>(
      qkv, 3072, w_out_b, 1024, nullptr, nullptr, 0,
      qkv + 1024, 3072, 1024, 4096, 1024, 512);
  // 4) x1_b = LN(x + P0 + P1 + b_out)
  ln_fuse<0,0><<<dim3(1024), blk, 0, stream>>>(
      qkv + 1024, qkv + 2048, 3072, x, b_out, ln1_g, ln1_b, x1_b);
  // 5) h = gelu(x1 @ w1^T + b1)                     [4096,4096]
  gemm_bt<1,0><<<dim3(32, 32, 1), blk, 0, stream>>>(
      x1_b, 1024, w1_b, 1024, b1, nullptr, 0, h, 4096, 0, 4096, 4096, 1024);
  // 6) split-K=2: P0/P1 = h @ w2^T partials
  gemm_bt<0,0><<<dim3(8, 32, 2), blk, 0, stream>>>(
      h, 4096, w2_b, 4096, nullptr, nullptr, 0,
      P0, 1024, 8388608, 4096, 1024, 2048);
  // 7) out(fp32) = LN(x1 + P0 + P1 + b2)
  ln_fuse<1,1><<<dim3(1024), blk, 0, stream>>>(
      P0, P1, 1024, x1_b, b2, ln2_g, ln2_b, out);
}